// Round 9
// baseline (70.376 us; speedup 1.0000x reference)
//
#include <hip/hip_runtime.h>
#include <hip/hip_bf16.h>
#include <stdint.h>

// QuantizedLinear: out[m][n] = (sum_k x[m][k]*W[n][k]) * scale + bias[n]
// M=256, K=4096, N=11008. W int8-valued -> exact in bf16; scale/bias f32 epilogue.
//
// R9 = R7 pipeline + split-K x2. Per-CU block-epochs unchanged (172) but
// concurrent block-streams double (2.69 -> 5.4/CU) so barrier convoys overlap.
// GEMM blocks write raw f32 partials to ws; reduce pass applies scale+bias.
// NSLOT=4 (18KB LDS) so 6+ blocks/CU fit. ws-size guarded: falls back to the
// proven single-K R7 path if workspace is too small.

#define MM 256
#define NN 11008
#define KK 4096
#define ROWB 144           // bf16 row pitch (128B data + 16B pad)
#define SLOTB (32 * ROWB)  // 4608 B per LDS slot
#define NSLOT 4

typedef __bf16 bf16x8 __attribute__((ext_vector_type(8)));
typedef float  f32x4  __attribute__((ext_vector_type(4)));

// ---- pass 1: x f32 [256][4096] -> bf16 packed in MFMA A-fragment order ----
// xf[(mb*128 + kb)*64 + l] = bf16x8 { x[mb*16 + (l&15)][kb*32 + (l>>4)*8 + j] }
__global__ void cvt_x_kernel(const float* __restrict__ x, bf16x8* __restrict__ xf) {
    int i  = blockIdx.x * 256 + threadIdx.x;   // 0..131071
    int l  = i & 63;
    int kb = (i >> 6) & 127;
    int mb = i >> 13;
    int m  = mb * 16 + (l & 15);
    int k  = kb * 32 + (l >> 4) * 8;
    const float* p = x + (size_t)m * KK + k;
    float4 v0 = *(const float4*)p;
    float4 v1 = *(const float4*)(p + 4);
    union { __bf16 b[8]; bf16x8 v; } t;
    t.b[0] = (__bf16)v0.x; t.b[1] = (__bf16)v0.y;
    t.b[2] = (__bf16)v0.z; t.b[3] = (__bf16)v0.w;
    t.b[4] = (__bf16)v1.x; t.b[5] = (__bf16)v1.y;
    t.b[6] = (__bf16)v1.z; t.b[7] = (__bf16)v1.w;
    xf[i] = t.v;
}

// ---- pass 2: GEMM (R7 loop). splitk=1: 1376 blocks, K-half each, raw partials
//      to pws[kh][256][11008]. splitk=0: 688 blocks, full K, scale+bias to out.
__global__ __launch_bounds__(256, 4) void qlin_gemm(
    const bf16x8* __restrict__ xf, const int* __restrict__ wq,
    const float* __restrict__ scale, const float* __restrict__ bias,
    float* __restrict__ out, float* __restrict__ pws, int splitk) {

    __shared__ __align__(16) char wsm[NSLOT * SLOTB];   // 18 KB

    const int tid  = threadIdx.x;
    const int lane = tid & 63;
    const int wid  = tid >> 6;          // 0..3
    const int nl   = lane & 15;
    const int qh   = lane >> 4;

    // XCD-grouped map: per XCD 43 strips x {mh} (fallback) or {mh,kh} (split).
    const int bid = blockIdx.x;
    const int xcd = bid & 7;
    const int seq = bid >> 3;
    int strip, mh, kh;
    if (splitk) { strip = xcd * 43 + (seq >> 2); mh = seq & 1; kh = (seq >> 1) & 1; }
    else        { strip = xcd * 43 + (seq >> 1); mh = seq & 1; kh = 0; }
    const int n0 = strip * 32;
    const int nt = splitk ? 32 : 64;        // K-tiles of 64
    const int k0 = kh << 11;                // element offset
    const int aoff = kh << 6;               // 32-elem chunk offset

    // --- W staging: thread t -> tile-row r = t>>3, k-slot s = t&7 (8 ints) ---
    const int wr = tid >> 3;
    const int ws = tid & 7;
    const int* wsrc = wq + (size_t)(n0 + wr) * KK + k0 + ws * 8;
    const int wdst  = wr * ROWB + ws * 16;

    // --- B fragment read offsets ---
    const int brd0 = nl * ROWB + qh * 16;
    const int brd1 = (16 + nl) * ROWB + qh * 16;

    // --- A fragments (packed, per-wave-private) ---
    const bf16x8* abase = xf + ((size_t)(mh * 8 + wid * 2) * 128 + aoff) * 64 + lane;

    f32x4 acc[2][2] = {};
    int4   R0[2], R1[2], R2[2], R3[2];      // W reg ring, tile u in slot u&3
    bf16x8 A0[4], A1[4], A2[4], A3[4];      // A bufs, tile u in buf u&3

    auto loadW = [&](int4 (&r)[2], int t) {
        const int* p = wsrc + t * 64;
        r[0] = *(const int4*)p;
        r[1] = *(const int4*)(p + 4);
    };
    auto loadA = [&](bf16x8 (&A)[4], int t) {
#pragma unroll
        for (int fmr = 0; fmr < 2; ++fmr)
#pragma unroll
            for (int kb = 0; kb < 2; ++kb)
                A[fmr * 2 + kb] = abase[((size_t)fmr * 128 + t * 2 + kb) * 64];
    };
    auto writeW = [&](const int4 (&r)[2], int slot) {
        union { __bf16 e[8]; bf16x8 v; } c;
        c.e[0] = (__bf16)(float)r[0].x; c.e[1] = (__bf16)(float)r[0].y;
        c.e[2] = (__bf16)(float)r[0].z; c.e[3] = (__bf16)(float)r[0].w;
        c.e[4] = (__bf16)(float)r[1].x; c.e[5] = (__bf16)(float)r[1].y;
        c.e[6] = (__bf16)(float)r[1].z; c.e[7] = (__bf16)(float)r[1].w;
        *(bf16x8*)(wsm + slot * SLOTB + wdst) = c.v;
    };
    auto compute = [&](const bf16x8 (&A)[4], int slot) {
        const char* B = wsm + slot * SLOTB;
#pragma unroll
        for (int kb = 0; kb < 2; ++kb) {
            bf16x8 b0 = *(const bf16x8*)(B + brd0 + kb * 64);
            bf16x8 b1 = *(const bf16x8*)(B + brd1 + kb * 64);
#pragma unroll
            for (int fmr = 0; fmr < 2; ++fmr) {
                acc[fmr][0] = __builtin_amdgcn_mfma_f32_16x16x32_bf16(
                    A[fmr * 2 + kb], b0, acc[fmr][0], 0, 0, 0);
                acc[fmr][1] = __builtin_amdgcn_mfma_f32_16x16x32_bf16(
                    A[fmr * 2 + kb], b1, acc[fmr][1], 0, 0, 0);
            }
        }
    };

    // ---- prologue ----
    loadW(R0, 0); loadW(R1, 1); loadW(R2, 2); loadW(R3, 3);
    loadA(A0, 0); loadA(A1, 1);
    writeW(R0, 0);
    writeW(R1, 1);
    asm volatile("s_waitcnt lgkmcnt(0)" ::: "memory");
    __builtin_amdgcn_s_barrier();

    // ---- iter t: loadA(t+2); loadW(t+4); writeW(tile t+2 -> slot (t+2)&3);
    //              compute(t, slot t&3); lgkm(0); barrier ----
#define STEP(T, AL, WL, WS, AC)                                      \
    {                                                                \
        const int t_ = (T);                                          \
        loadA(AL, (t_ + 2 < nt) ? t_ + 2 : nt - 1);                  \
        loadW(WL, (t_ + 4 < nt) ? t_ + 4 : nt - 1);                  \
        writeW(WS, (t_ + 2) & 3);                                    \
        compute(AC, t_ & 3);                                         \
        asm volatile("s_waitcnt lgkmcnt(0)" ::: "memory");           \
        __builtin_amdgcn_s_barrier();                                \
    }

#pragma unroll 1
    for (int tq = 0; tq < (nt >> 2); ++tq) {
        const int t0 = tq * 4;
        STEP(t0 + 0, A2, R0, R2, A0)
        STEP(t0 + 1, A3, R1, R3, A1)
        STEP(t0 + 2, A0, R2, R0, A2)
        STEP(t0 + 3, A1, R3, R1, A3)
    }
#undef STEP

    // ---- epilogue ----
    const int erow0 = qh * 4;
    if (splitk) {
        float* pb = pws + (size_t)kh * (MM * NN);
#pragma unroll
        for (int fn = 0; fn < 2; ++fn) {
            const int n = n0 + fn * 16 + nl;
#pragma unroll
            for (int fmr = 0; fmr < 2; ++fmr) {
                const int m = mh * 128 + wid * 32 + fmr * 16 + erow0;
#pragma unroll
                for (int r = 0; r < 4; ++r)
                    pb[(size_t)(m + r) * NN + n] = acc[fmr][fn][r];
            }
        }
    } else {
        const float sc = scale[0];
#pragma unroll
        for (int fn = 0; fn < 2; ++fn) {
            const int n = n0 + fn * 16 + nl;
            const float bv = bias[n];
#pragma unroll
            for (int fmr = 0; fmr < 2; ++fmr) {
                const int m = mh * 128 + wid * 32 + fmr * 16 + erow0;
#pragma unroll
                for (int r = 0; r < 4; ++r)
                    out[(size_t)(m + r) * NN + n] = acc[fmr][fn][r] * sc + bv;
            }
        }
    }
}

// ---- pass 3: out = (p0 + p1) * scale + bias ----
__global__ void reduce_kernel(const float* __restrict__ pws,
                              const float* __restrict__ scale,
                              const float* __restrict__ bias,
                              float* __restrict__ out) {
    const int i4 = (blockIdx.x * 256 + threadIdx.x) * 4;   // < MM*NN
    const int n  = i4 % NN;                                 // NN % 4 == 0
    const float sc = scale[0];
    float4 a = *(const float4*)(pws + i4);
    float4 b = *(const float4*)(pws + (size_t)MM * NN + i4);
    float4 c = *(const float4*)(bias + n);
    float4 o;
    o.x = (a.x + b.x) * sc + c.x;
    o.y = (a.y + b.y) * sc + c.y;
    o.z = (a.z + b.z) * sc + c.z;
    o.w = (a.w + b.w) * sc + c.w;
    *(float4*)(out + i4) = o;
}

extern "C" void kernel_launch(void* const* d_in, const int* in_sizes, int n_in,
                              void* d_out, int out_size, void* d_ws, size_t ws_size,
                              hipStream_t stream) {
    const float* x     = (const float*)d_in[0];
    const int*   wq    = (const int*)d_in[1];
    const float* scale = (const float*)d_in[2];
    const float* bias  = (const float*)d_in[3];
    float* out = (float*)d_out;
    bf16x8* xf = (bf16x8*)d_ws;                              // 2 MB packed A
    float* pws = (float*)((char*)d_ws + (2u << 20));         // 22.5 MB partials

    const size_t need = (2u << 20) + 2ull * MM * NN * 4ull;
    const int splitk = (ws_size >= need) ? 1 : 0;

    cvt_x_kernel<<<dim3(MM * KK / (256 * 4 * 2)), dim3(256), 0, stream>>>(x, xf);
    if (splitk) {
        qlin_gemm<<<dim3(1376), dim3(256), 0, stream>>>(xf, wq, scale, bias, out, pws, 1);
        reduce_kernel<<<dim3(MM * NN / 1024), dim3(256), 0, stream>>>(pws, scale, bias, out);
    } else {
        qlin_gemm<<<dim3(688), dim3(256), 0, stream>>>(xf, wq, scale, bias, out, pws, 0);
    }
}

// Round 10
// 53.348 us; speedup vs baseline: 1.3192x; 1.3192x over previous
//
#include <hip/hip_runtime.h>
#include <hip/hip_bf16.h>
#include <stdint.h>

// QuantizedLinear: out[m][n] = (sum_k x[m][k]*W[n][k]) * scale + bias[n]
// M=256, K=4096, N=11008. W int8-valued -> exact in bf16; scale/bias f32 epilogue.
//
// R10: W requested EXACTLY ONCE (R6-R9 invariant: 2x W-request volume pinned
// ~6.6 TB/s through the L2-fill path -> ~55us floor; halving requests halves it).
// Grid = 256 blocks (1/CU, zero imbalance; 11008 = 256*43). Block = 512 thr
// (8 waves), tile 256m x 43n (padded to 48 = 3x16), BK=128, NT=32.
// Per wave: 32m x 48n -> 24 MFMA/iter (3x R7 density), 64 wave-iters/SIMD.
// A (2MB packed frags) is L2-resident per XCD; re-read per n-swath (512MB L2).
// Pipeline = R7 dataflow: W global->reg ring-4 (2-iter gap) -> write-side cvt
// -> 4-slot bf16 LDS ring (272B pitch, 2-way banks free); A ping-pong reloaded
// right after consume; one lgkmcnt(0)+s_barrier per iter; vmcnt NEVER drained.

#define MM 256
#define NN 11008
#define KK 4096
#define BK 128
#define NT (KK / BK)        // 32
#define NSW 43              // real n-cols per block (11008 = 256*43)
#define NPD 48              // padded n-tile (3 x 16)
#define ROWB 272            // bf16 row pitch bytes (256 data + 16 pad)
#define SLOTB (NPD * ROWB)  // 13056 B per LDS slot
#define NSLOT 4             // 52224 B LDS total

typedef __bf16 bf16x8 __attribute__((ext_vector_type(8)));
typedef float  f32x4  __attribute__((ext_vector_type(4)));

// ---- pass 1: x f32 [256][4096] -> bf16 packed in MFMA A-fragment order ----
// xf[(mb*128 + kb)*64 + l] = bf16x8 { x[mb*16 + (l&15)][kb*32 + (l>>4)*8 + j] }
__global__ void cvt_x_kernel(const float* __restrict__ x, bf16x8* __restrict__ xf) {
    int i  = blockIdx.x * 256 + threadIdx.x;   // 0..131071
    int l  = i & 63;
    int kb = (i >> 6) & 127;
    int mb = i >> 13;
    int m  = mb * 16 + (l & 15);
    int k  = kb * 32 + (l >> 4) * 8;
    const float* p = x + (size_t)m * KK + k;
    float4 v0 = *(const float4*)p;
    float4 v1 = *(const float4*)(p + 4);
    union { __bf16 b[8]; bf16x8 v; } t;
    t.b[0] = (__bf16)v0.x; t.b[1] = (__bf16)v0.y;
    t.b[2] = (__bf16)v0.z; t.b[3] = (__bf16)v0.w;
    t.b[4] = (__bf16)v1.x; t.b[5] = (__bf16)v1.y;
    t.b[6] = (__bf16)v1.z; t.b[7] = (__bf16)v1.w;
    xf[i] = t.v;
}

// ---- pass 2: GEMM. 512 thr = 8 waves; wave w owns m-rows [w*32, +32) x 48 n ----
__global__ __launch_bounds__(512, 2) void qlin_gemm(
    const bf16x8* __restrict__ xf, const int* __restrict__ wq,
    const float* __restrict__ scale, const float* __restrict__ bias,
    float* __restrict__ out) {

    __shared__ __align__(16) char wsm[NSLOT * SLOTB];   // 52224 B

    const int tid  = threadIdx.x;
    const int lane = tid & 63;
    const int wid  = tid >> 6;          // 0..7
    const int nl   = lane & 15;
    const int qh   = lane >> 4;

    const int n0 = blockIdx.x * NSW;    // 0..10965

    // --- W staging map: threads 0..383 (waves 0-5); thread -> tile-row sr = tid>>3
    //     (0..47), k-slot sl = tid&7 (16 ints = 4 int4). Waves 6,7 skip (uniform).
    const bool stager = (tid < 384);
    const int sr = tid >> 3;
    const int sl = tid & 7;
    int grow = n0 + sr; if (grow > NN - 1) grow = NN - 1;   // pad rows clamp
    const int* wsrc = wq + (size_t)grow * KK + sl * 16;
    const int wdst  = sr * ROWB + sl * 32;

    // --- A fragments (packed, L2-resident): mb = wid*2 + fmr ---
    const bf16x8* abase = xf + ((size_t)(wid * 2) * 128) * 64 + lane;

    f32x4 acc[2][3] = {};
    int4   R0[4], R1[4], R2[4], R3[4];   // W reg ring: tile u in slot u&3
    bf16x8 AA[8], AB[8];                 // A ping-pong: tile u in buf u&1; [fmr*4+kb]

    auto loadW = [&](int4 (&r)[4], int t) {
        if (stager) {
            const int* p = wsrc + t * BK;
#pragma unroll
            for (int j = 0; j < 4; ++j)
                r[j] = *(const int4*)(p + j * 4);
        }
    };
    auto loadA = [&](bf16x8 (&A)[8], int t) {
#pragma unroll
        for (int fmr = 0; fmr < 2; ++fmr)
#pragma unroll
            for (int kb = 0; kb < 4; ++kb)
                A[fmr * 4 + kb] = abase[((size_t)fmr * 128 + t * 4 + kb) * 64];
    };
    auto writeW = [&](const int4 (&r)[4], int slotoff) {
        if (stager) {
            union { __bf16 e[16]; bf16x8 v[2]; } c;
#pragma unroll
            for (int j = 0; j < 4; ++j) {
                c.e[j * 4 + 0] = (__bf16)(float)r[j].x;
                c.e[j * 4 + 1] = (__bf16)(float)r[j].y;
                c.e[j * 4 + 2] = (__bf16)(float)r[j].z;
                c.e[j * 4 + 3] = (__bf16)(float)r[j].w;
            }
            char* d = wsm + slotoff + wdst;
            *(bf16x8*)d = c.v[0];
            *(bf16x8*)(d + 16) = c.v[1];
        }
    };
    auto compute = [&](const bf16x8 (&A)[8], int slotoff) {
        const char* B = wsm + slotoff;
#pragma unroll
        for (int ks = 0; ks < 4; ++ks) {
            bf16x8 b[3];
#pragma unroll
            for (int fn = 0; fn < 3; ++fn)
                b[fn] = *(const bf16x8*)(B + (fn * 16 + nl) * ROWB + ks * 64 + qh * 16);
#pragma unroll
            for (int fmr = 0; fmr < 2; ++fmr)
#pragma unroll
                for (int fn = 0; fn < 3; ++fn)
                    acc[fmr][fn] = __builtin_amdgcn_mfma_f32_16x16x32_bf16(
                        A[fmr * 4 + ks], b[fn], acc[fmr][fn], 0, 0, 0);
        }
    };

    // ---- prologue: W(0..3) -> reg ring; A(0),A(1); tiles 0,1 -> LDS slots 0,1 ----
    loadW(R0, 0); loadW(R1, 1); loadW(R2, 2); loadW(R3, 3);
    loadA(AA, 0); loadA(AB, 1);
    writeW(R0, 0 * SLOTB);
    writeW(R1, 1 * SLOTB);
    asm volatile("s_waitcnt lgkmcnt(0)" ::: "memory");
    __builtin_amdgcn_s_barrier();

    // ---- iter t: loadW(W(t+4)); writeW(regs tile t+2 -> slot (t+2)&3);
    //              compute(t, slot t&3); loadA(t+2 into just-freed buf);
    //              lgkm(0); barrier ----
#define STEP(T, WL, WS, AC)                                          \
    {                                                                \
        const int t_ = (T);                                          \
        loadW(WL, (t_ + 4 < NT) ? t_ + 4 : NT - 1);                  \
        writeW(WS, ((t_ + 2) & 3) * SLOTB);                          \
        compute(AC, (t_ & 3) * SLOTB);                               \
        loadA(AC, (t_ + 2 < NT) ? t_ + 2 : NT - 1);                  \
        asm volatile("s_waitcnt lgkmcnt(0)" ::: "memory");           \
        __builtin_amdgcn_s_barrier();                                \
    }

#pragma unroll 1
    for (int tq = 0; tq < NT / 4; ++tq) {
        const int t0 = tq * 4;
        STEP(t0 + 0, R0, R2, AA)   // reload R0 <- W(t+4); publish tile t+2 (R2)
        STEP(t0 + 1, R1, R3, AB)
        STEP(t0 + 2, R2, R0, AA)
        STEP(t0 + 3, R3, R1, AB)
    }
#undef STEP

    // ---- epilogue: D layout col=nl, row=qh*4+r; mask pad cols; y=acc*sc+bias ----
    const float sc = scale[0];
#pragma unroll
    for (int fn = 0; fn < 3; ++fn) {
        const int ncol = fn * 16 + nl;
        if (ncol < NSW) {
            const int n = n0 + ncol;
            const float bv = bias[n];
#pragma unroll
            for (int fmr = 0; fmr < 2; ++fmr) {
                const int m = wid * 32 + fmr * 16 + qh * 4;
#pragma unroll
                for (int r = 0; r < 4; ++r)
                    out[(size_t)(m + r) * NN + n] = acc[fmr][fn][r] * sc + bv;
            }
        }
    }
}

extern "C" void kernel_launch(void* const* d_in, const int* in_sizes, int n_in,
                              void* d_out, int out_size, void* d_ws, size_t ws_size,
                              hipStream_t stream) {
    const float* x     = (const float*)d_in[0];
    const int*   wq    = (const int*)d_in[1];
    const float* scale = (const float*)d_in[2];
    const float* bias  = (const float*)d_in[3];
    float* out = (float*)d_out;
    bf16x8* xf = (bf16x8*)d_ws;   // 2 MB packed-A scratch

    cvt_x_kernel<<<dim3(MM * KK / (256 * 8)), dim3(256), 0, stream>>>(x, xf);
    qlin_gemm<<<dim3(NN / NSW), dim3(512), 0, stream>>>(xf, wq, scale, bias, out);
}

// Round 11
// 51.592 us; speedup vs baseline: 1.3641x; 1.0340x over previous
//
#include <hip/hip_runtime.h>
#include <hip/hip_bf16.h>
#include <stdint.h>

// QuantizedLinear: out[m][n] = (sum_k x[m][k]*W[n][k]) * scale + bias[n]
// M=256, K=4096, N=11008. W int8-valued -> exact in bf16; scale/bias f32 epilogue.
//
// R11 = R10 (W requested exactly once; 256 blocks = 1/CU; 512 thr = 8 waves;
// block tile 256m x 43n; BK=128, NT=32; R7 dataflow pipeline) plus:
//  - EXACT 43-row staging (344 stager threads) -- kills the 48-row pad's
//    +11.6% W traffic and all row clamping.
//  - s_setprio(1) around the MFMA/ds_read cluster (T5: this structure has
//    stager/non-stager wave role-split, the regime where setprio pays).
//  - B-frag read rows clamped to 42 for the pad cols (precomputed, masked
//    at store; keeps all LDS reads in-bounds with the tight 43-row slots).
// vmcnt NEVER drained; one lgkmcnt(0) + s_barrier per iter. NO nontemporal
// hints on W: timed replays get ~half of W from L3 (FETCH ~100MB in R6-R9),
// and nt would forfeit that.

#define MM 256
#define NN 11008
#define KK 4096
#define BK 128
#define NT (KK / BK)        // 32
#define NSW 43              // n-cols per block (11008 = 256*43), staged EXACTLY
#define ROWB 272            // bf16 row pitch bytes (256 data + 16 pad)
#define SLOTB (NSW * ROWB)  // 11696 B per LDS slot
#define NSLOT 4             // 46784 B LDS total

typedef __bf16 bf16x8 __attribute__((ext_vector_type(8)));
typedef float  f32x4  __attribute__((ext_vector_type(4)));

// ---- pass 1: x f32 [256][4096] -> bf16 packed in MFMA A-fragment order ----
// xf[(mb*128 + kb)*64 + l] = bf16x8 { x[mb*16 + (l&15)][kb*32 + (l>>4)*8 + j] }
__global__ void cvt_x_kernel(const float* __restrict__ x, bf16x8* __restrict__ xf) {
    int i  = blockIdx.x * 256 + threadIdx.x;   // 0..131071
    int l  = i & 63;
    int kb = (i >> 6) & 127;
    int mb = i >> 13;
    int m  = mb * 16 + (l & 15);
    int k  = kb * 32 + (l >> 4) * 8;
    const float* p = x + (size_t)m * KK + k;
    float4 v0 = *(const float4*)p;
    float4 v1 = *(const float4*)(p + 4);
    union { __bf16 b[8]; bf16x8 v; } t;
    t.b[0] = (__bf16)v0.x; t.b[1] = (__bf16)v0.y;
    t.b[2] = (__bf16)v0.z; t.b[3] = (__bf16)v0.w;
    t.b[4] = (__bf16)v1.x; t.b[5] = (__bf16)v1.y;
    t.b[6] = (__bf16)v1.z; t.b[7] = (__bf16)v1.w;
    xf[i] = t.v;
}

// ---- pass 2: GEMM. 512 thr = 8 waves; wave w owns m-rows [w*32, +32) x 43 n ----
__global__ __launch_bounds__(512, 2) void qlin_gemm(
    const bf16x8* __restrict__ xf, const int* __restrict__ wq,
    const float* __restrict__ scale, const float* __restrict__ bias,
    float* __restrict__ out) {

    __shared__ __align__(16) char wsm[NSLOT * SLOTB];   // 46784 B

    const int tid  = threadIdx.x;
    const int lane = tid & 63;
    const int wid  = tid >> 6;          // 0..7
    const int nl   = lane & 15;
    const int qh   = lane >> 4;

    const int n0 = blockIdx.x * NSW;    // 0..10965; last block row = 11007 exactly

    // --- W staging: threads 0..343; thread -> tile-row sr = tid>>3 (0..42),
    //     k-slot sl = tid&7 (16 ints = 4 int4 = 64B -> 32B bf16). No clamps.
    const bool stager = (tid < NSW * 8);
    const int sr = tid >> 3;
    const int sl = tid & 7;
    const int* wsrc = wq + (size_t)(n0 + sr) * KK + sl * 16;
    const int wdst  = sr * ROWB + sl * 32;

    // --- B fragment read rows (clamped for pad cols; those cols masked at store) ---
    int brd[3];
#pragma unroll
    for (int fn = 0; fn < 3; ++fn) {
        int r = fn * 16 + nl; if (r > NSW - 1) r = NSW - 1;
        brd[fn] = r * ROWB + qh * 16;
    }

    // --- A fragments (packed, L2/L3-resident): mb = wid*2 + fmr ---
    const bf16x8* abase = xf + ((size_t)(wid * 2) * 128) * 64 + lane;

    f32x4 acc[2][3] = {};
    int4   R0[4], R1[4], R2[4], R3[4];   // W reg ring: tile u in slot u&3
    bf16x8 AA[8], AB[8];                 // A ping-pong: tile u in buf u&1; [fmr*4+kb]

    auto loadW = [&](int4 (&r)[4], int t) {
        if (stager) {
            const int* p = wsrc + t * BK;
#pragma unroll
            for (int j = 0; j < 4; ++j)
                r[j] = *(const int4*)(p + j * 4);
        }
    };
    auto loadA = [&](bf16x8 (&A)[8], int t) {
#pragma unroll
        for (int fmr = 0; fmr < 2; ++fmr)
#pragma unroll
            for (int kb = 0; kb < 4; ++kb)
                A[fmr * 4 + kb] = abase[((size_t)fmr * 128 + t * 4 + kb) * 64];
    };
    auto writeW = [&](const int4 (&r)[4], int slotoff) {
        if (stager) {
            union { __bf16 e[16]; bf16x8 v[2]; } c;
#pragma unroll
            for (int j = 0; j < 4; ++j) {
                c.e[j * 4 + 0] = (__bf16)(float)r[j].x;
                c.e[j * 4 + 1] = (__bf16)(float)r[j].y;
                c.e[j * 4 + 2] = (__bf16)(float)r[j].z;
                c.e[j * 4 + 3] = (__bf16)(float)r[j].w;
            }
            char* d = wsm + slotoff + wdst;
            *(bf16x8*)d = c.v[0];
            *(bf16x8*)(d + 16) = c.v[1];
        }
    };
    auto compute = [&](const bf16x8 (&A)[8], int slotoff) {
        const char* B = wsm + slotoff;
        __builtin_amdgcn_s_setprio(1);
#pragma unroll
        for (int ks = 0; ks < 4; ++ks) {
            bf16x8 b[3];
#pragma unroll
            for (int fn = 0; fn < 3; ++fn)
                b[fn] = *(const bf16x8*)(B + brd[fn] + ks * 64);
#pragma unroll
            for (int fmr = 0; fmr < 2; ++fmr)
#pragma unroll
                for (int fn = 0; fn < 3; ++fn)
                    acc[fmr][fn] = __builtin_amdgcn_mfma_f32_16x16x32_bf16(
                        A[fmr * 4 + ks], b[fn], acc[fmr][fn], 0, 0, 0);
        }
        __builtin_amdgcn_s_setprio(0);
    };

    // ---- prologue: W(0..3) -> reg ring; A(0),A(1); tiles 0,1 -> LDS slots 0,1 ----
    loadW(R0, 0); loadW(R1, 1); loadW(R2, 2); loadW(R3, 3);
    loadA(AA, 0); loadA(AB, 1);
    writeW(R0, 0 * SLOTB);
    writeW(R1, 1 * SLOTB);
    asm volatile("s_waitcnt lgkmcnt(0)" ::: "memory");
    __builtin_amdgcn_s_barrier();

    // ---- iter t: loadW(W(t+4)); writeW(regs tile t+2 -> slot (t+2)&3);
    //              compute(t, slot t&3); loadA(t+2 into just-freed buf);
    //              lgkm(0); barrier ----
#define STEP(T, WL, WS, AC)                                          \
    {                                                                \
        const int t_ = (T);                                          \
        loadW(WL, (t_ + 4 < NT) ? t_ + 4 : NT - 1);                  \
        writeW(WS, ((t_ + 2) & 3) * SLOTB);                          \
        compute(AC, (t_ & 3) * SLOTB);                               \
        loadA(AC, (t_ + 2 < NT) ? t_ + 2 : NT - 1);                  \
        asm volatile("s_waitcnt lgkmcnt(0)" ::: "memory");           \
        __builtin_amdgcn_s_barrier();                                \
    }

#pragma unroll 1
    for (int tq = 0; tq < NT / 4; ++tq) {
        const int t0 = tq * 4;
        STEP(t0 + 0, R0, R2, AA)   // reload R0 <- W(t+4); publish tile t+2 (R2)
        STEP(t0 + 1, R1, R3, AB)
        STEP(t0 + 2, R2, R0, AA)
        STEP(t0 + 3, R3, R1, AB)
    }
#undef STEP

    // ---- epilogue: D layout col=nl, row=qh*4+r; mask pad cols; y=acc*sc+bias ----
    const float sc = scale[0];
#pragma unroll
    for (int fn = 0; fn < 3; ++fn) {
        const int ncol = fn * 16 + nl;
        if (ncol < NSW) {
            const int n = n0 + ncol;
            const float bv = bias[n];
#pragma unroll
            for (int fmr = 0; fmr < 2; ++fmr) {
                const int m = wid * 32 + fmr * 16 + qh * 4;
#pragma unroll
                for (int r = 0; r < 4; ++r)
                    out[(size_t)(m + r) * NN + n] = acc[fmr][fn][r] * sc + bv;
            }
        }
    }
}

extern "C" void kernel_launch(void* const* d_in, const int* in_sizes, int n_in,
                              void* d_out, int out_size, void* d_ws, size_t ws_size,
                              hipStream_t stream) {
    const float* x     = (const float*)d_in[0];
    const int*   wq    = (const int*)d_in[1];
    const float* scale = (const float*)d_in[2];
    const float* bias  = (const float*)d_in[3];
    float* out = (float*)d_out;
    bf16x8* xf = (bf16x8*)d_ws;   // 2 MB packed-A scratch

    cvt_x_kernel<<<dim3(MM * KK / (256 * 8)), dim3(256), 0, stream>>>(x, xf);
    qlin_gemm<<<dim3(NN / NSW), dim3(512), 0, stream>>>(xf, wq, scale, bias, out);
}

// Round 12
// 51.516 us; speedup vs baseline: 1.3661x; 1.0015x over previous
//
#include <hip/hip_runtime.h>
#include <hip/hip_bf16.h>
#include <stdint.h>

// QuantizedLinear: out[m][n] = (sum_k x[m][k]*W[n][k]) * scale + bias[n]
// M=256, K=4096, N=11008. W int8-valued -> exact in bf16; scale/bias f32 epilogue.
//
// R12 = R11 (W requested exactly once; 256 blocks = 1/CU; 512 thr = 8 waves;
// tile 256m x 43n; BK=128, NT=32; W global->reg ring-4 -> write-side cvt ->
// 4-slot bf16 LDS ring; A packed-frag ping-pong; setprio around MFMA cluster;
// vmcnt NEVER drained) with ONE sync change:
//  - barrier every 2 iters (pair-fused epochs). Writes are 2 slots ahead of
//    reads, so in a pair {t,t+1} writes hit slots {t+2,t+3} and reads hit
//    {t,t+1} (mod 4) -- disjoint; write->read of any slot still crosses one
//    lgkmcnt(0)+s_barrier. 32 -> 16 barrier convoys, zero VGPR/lookahead cost.

#define MM 256
#define NN 11008
#define KK 4096
#define BK 128
#define NT (KK / BK)        // 32
#define NSW 43              // n-cols per block (11008 = 256*43), staged EXACTLY
#define ROWB 272            // bf16 row pitch bytes (256 data + 16 pad)
#define SLOTB (NSW * ROWB)  // 11696 B per LDS slot
#define NSLOT 4             // 46784 B LDS total

typedef __bf16 bf16x8 __attribute__((ext_vector_type(8)));
typedef float  f32x4  __attribute__((ext_vector_type(4)));

// ---- pass 1: x f32 [256][4096] -> bf16 packed in MFMA A-fragment order ----
// xf[(mb*128 + kb)*64 + l] = bf16x8 { x[mb*16 + (l&15)][kb*32 + (l>>4)*8 + j] }
__global__ void cvt_x_kernel(const float* __restrict__ x, bf16x8* __restrict__ xf) {
    int i  = blockIdx.x * 256 + threadIdx.x;   // 0..131071
    int l  = i & 63;
    int kb = (i >> 6) & 127;
    int mb = i >> 13;
    int m  = mb * 16 + (l & 15);
    int k  = kb * 32 + (l >> 4) * 8;
    const float* p = x + (size_t)m * KK + k;
    float4 v0 = *(const float4*)p;
    float4 v1 = *(const float4*)(p + 4);
    union { __bf16 b[8]; bf16x8 v; } t;
    t.b[0] = (__bf16)v0.x; t.b[1] = (__bf16)v0.y;
    t.b[2] = (__bf16)v0.z; t.b[3] = (__bf16)v0.w;
    t.b[4] = (__bf16)v1.x; t.b[5] = (__bf16)v1.y;
    t.b[6] = (__bf16)v1.z; t.b[7] = (__bf16)v1.w;
    xf[i] = t.v;
}

// ---- pass 2: GEMM. 512 thr = 8 waves; wave w owns m-rows [w*32, +32) x 43 n ----
__global__ __launch_bounds__(512, 2) void qlin_gemm(
    const bf16x8* __restrict__ xf, const int* __restrict__ wq,
    const float* __restrict__ scale, const float* __restrict__ bias,
    float* __restrict__ out) {

    __shared__ __align__(16) char wsm[NSLOT * SLOTB];   // 46784 B

    const int tid  = threadIdx.x;
    const int lane = tid & 63;
    const int wid  = tid >> 6;          // 0..7
    const int nl   = lane & 15;
    const int qh   = lane >> 4;

    const int n0 = blockIdx.x * NSW;    // 0..10965; last block row = 11007 exactly

    // --- W staging: threads 0..343; thread -> tile-row sr = tid>>3 (0..42),
    //     k-slot sl = tid&7 (16 ints = 4 int4 = 64B -> 32B bf16). No clamps.
    const bool stager = (tid < NSW * 8);
    const int sr = tid >> 3;
    const int sl = tid & 7;
    const int* wsrc = wq + (size_t)(n0 + sr) * KK + sl * 16;
    const int wdst  = sr * ROWB + sl * 32;

    // --- B fragment read rows (clamped for pad cols; those cols masked at store) ---
    int brd[3];
#pragma unroll
    for (int fn = 0; fn < 3; ++fn) {
        int r = fn * 16 + nl; if (r > NSW - 1) r = NSW - 1;
        brd[fn] = r * ROWB + qh * 16;
    }

    // --- A fragments (packed, L2/L3-resident): mb = wid*2 + fmr ---
    const bf16x8* abase = xf + ((size_t)(wid * 2) * 128) * 64 + lane;

    f32x4 acc[2][3] = {};
    int4   R0[4], R1[4], R2[4], R3[4];   // W reg ring: tile u in slot u&3
    bf16x8 AA[8], AB[8];                 // A ping-pong: tile u in buf u&1; [fmr*4+kb]

    auto loadW = [&](int4 (&r)[4], int t) {
        if (stager) {
            const int* p = wsrc + t * BK;
#pragma unroll
            for (int j = 0; j < 4; ++j)
                r[j] = *(const int4*)(p + j * 4);
        }
    };
    auto loadA = [&](bf16x8 (&A)[8], int t) {
#pragma unroll
        for (int fmr = 0; fmr < 2; ++fmr)
#pragma unroll
            for (int kb = 0; kb < 4; ++kb)
                A[fmr * 4 + kb] = abase[((size_t)fmr * 128 + t * 4 + kb) * 64];
    };
    auto writeW = [&](const int4 (&r)[4], int slotoff) {
        if (stager) {
            union { __bf16 e[16]; bf16x8 v[2]; } c;
#pragma unroll
            for (int j = 0; j < 4; ++j) {
                c.e[j * 4 + 0] = (__bf16)(float)r[j].x;
                c.e[j * 4 + 1] = (__bf16)(float)r[j].y;
                c.e[j * 4 + 2] = (__bf16)(float)r[j].z;
                c.e[j * 4 + 3] = (__bf16)(float)r[j].w;
            }
            char* d = wsm + slotoff + wdst;
            *(bf16x8*)d = c.v[0];
            *(bf16x8*)(d + 16) = c.v[1];
        }
    };
    auto compute = [&](const bf16x8 (&A)[8], int slotoff) {
        const char* B = wsm + slotoff;
        __builtin_amdgcn_s_setprio(1);
#pragma unroll
        for (int ks = 0; ks < 4; ++ks) {
            bf16x8 b[3];
#pragma unroll
            for (int fn = 0; fn < 3; ++fn)
                b[fn] = *(const bf16x8*)(B + brd[fn] + ks * 64);
#pragma unroll
            for (int fmr = 0; fmr < 2; ++fmr)
#pragma unroll
                for (int fn = 0; fn < 3; ++fn)
                    acc[fmr][fn] = __builtin_amdgcn_mfma_f32_16x16x32_bf16(
                        A[fmr * 4 + ks], b[fn], acc[fmr][fn], 0, 0, 0);
        }
        __builtin_amdgcn_s_setprio(0);
    };

    // ---- prologue: W(0..3) -> reg ring; A(0),A(1); tiles 0,1 -> LDS slots 0,1 ----
    loadW(R0, 0); loadW(R1, 1); loadW(R2, 2); loadW(R3, 3);
    loadA(AA, 0); loadA(AB, 1);
    writeW(R0, 0 * SLOTB);
    writeW(R1, 1 * SLOTB);
    asm volatile("s_waitcnt lgkmcnt(0)" ::: "memory");
    __builtin_amdgcn_s_barrier();

    // ---- iter t: loadW(W(t+4)); writeW(tile t+2 -> slot (t+2)&3);
    //              compute(t, slot t&3); loadA(t+2 into just-freed buf).
    //      Sync only at pair boundaries (every 2 iters). ----
#define STEP_A(T, WL, WS, AC)                                        \
    {                                                                \
        const int t_ = (T);                                          \
        loadW(WL, (t_ + 4 < NT) ? t_ + 4 : NT - 1);                  \
        writeW(WS, ((t_ + 2) & 3) * SLOTB);                          \
        compute(AC, (t_ & 3) * SLOTB);                               \
        loadA(AC, (t_ + 2 < NT) ? t_ + 2 : NT - 1);                  \
    }
#define STEP_B(T, WL, WS, AC)                                        \
    {                                                                \
        STEP_A(T, WL, WS, AC)                                        \
        asm volatile("s_waitcnt lgkmcnt(0)" ::: "memory");           \
        __builtin_amdgcn_s_barrier();                                \
    }

#pragma unroll 1
    for (int tq = 0; tq < NT / 4; ++tq) {
        const int t0 = tq * 4;
        STEP_A(t0 + 0, R0, R2, AA)   // reload R0 <- W(t+4); publish tile t+2 (R2)
        STEP_B(t0 + 1, R1, R3, AB)
        STEP_A(t0 + 2, R2, R0, AA)
        STEP_B(t0 + 3, R3, R1, AB)
    }
#undef STEP_A
#undef STEP_B

    // ---- epilogue: D layout col=nl, row=qh*4+r; mask pad cols; y=acc*sc+bias ----
    const float sc = scale[0];
#pragma unroll
    for (int fn = 0; fn < 3; ++fn) {
        const int ncol = fn * 16 + nl;
        if (ncol < NSW) {
            const int n = n0 + ncol;
            const float bv = bias[n];
#pragma unroll
            for (int fmr = 0; fmr < 2; ++fmr) {
                const int m = wid * 32 + fmr * 16 + qh * 4;
#pragma unroll
                for (int r = 0; r < 4; ++r)
                    out[(size_t)(m + r) * NN + n] = acc[fmr][fn][r] * sc + bv;
            }
        }
    }
}

extern "C" void kernel_launch(void* const* d_in, const int* in_sizes, int n_in,
                              void* d_out, int out_size, void* d_ws, size_t ws_size,
                              hipStream_t stream) {
    const float* x     = (const float*)d_in[0];
    const int*   wq    = (const int*)d_in[1];
    const float* scale = (const float*)d_in[2];
    const float* bias  = (const float*)d_in[3];
    float* out = (float*)d_out;
    bf16x8* xf = (bf16x8*)d_ws;   // 2 MB packed-A scratch

    cvt_x_kernel<<<dim3(MM * KK / (256 * 8)), dim3(256), 0, stream>>>(x, xf);
    qlin_gemm<<<dim3(NN / NSW), dim3(512), 0, stream>>>(xf, wq, scale, bias, out);
}